// Round 1
// baseline (174.916 us; speedup 1.0000x reference)
//
#include <hip/hip_runtime.h>
#include <hip/hip_fp16.h>

// Problem: Topo_60653528154131
//   x:[256,3,256,25] f32, centres:[64,2] f32, sharpness:[64,2] f32 -> out:[64] f32
//
// Pipeline:
//   K1 k_mean : m[n,v] = mean_{c,t} x[n,c,t,v]           (19.7 MB read, memory-bound)
//   K2 k_feat : feat[n,w] = ||m[n,:] - m[n,w]||          + global min/max (atomics)
//   K3 k_dist : D16[i,j] = fp16(||feat_i - feat_j||)     (unnormalized! MST is scale-inv)
//   K4 k_mst  : Prim MST (1 wave, DPP argmin, D in LDS), deaths *= 1/(max-min),
//               structure-element layer -> out[64]
//
// ws layout (needs 196608 B):
//   m    [6400] f32  @ 0
//   mm   [2]    u32  @ 25600   (min,max of feat as ordered-uint bits; feat>=0)
//   feat [6400] f32  @ 32768
//   D16  [65536] u16 @ 65536

#define WS_M    0
#define WS_MM   25600
#define WS_FEAT 32768
#define WS_D16  65536

// ---------------- K1: channel+time mean ----------------
// Per block: one n. Slice is 3*256*25 = 19200 floats. 200 threads x float4,
// stride 800 floats/iter (800 % 25 == 0 -> each thread's v-indices are fixed).
__global__ void k_mean(const float* __restrict__ x, float* __restrict__ m,
                       unsigned int* __restrict__ mm) {
    const int n = blockIdx.x;
    const int tid = threadIdx.x;
    if (n == 0 && tid == 0) { mm[0] = 0x7F800000u; mm[1] = 0u; }  // +inf, 0
    __shared__ float sums[25];
    if (tid < 25) sums[tid] = 0.0f;
    __syncthreads();
    if (tid < 200) {
        const float* base = x + (long)n * 19200 + 4 * tid;
        float a0 = 0.f, a1 = 0.f, a2 = 0.f, a3 = 0.f;
        #pragma unroll
        for (int i = 0; i < 24; ++i) {
            float4 v = *reinterpret_cast<const float4*>(base + 800 * i);
            a0 += v.x; a1 += v.y; a2 += v.z; a3 += v.w;
        }
        const int v0 = (4 * tid) % 25;
        atomicAdd(&sums[v0], a0);
        atomicAdd(&sums[(v0 + 1) % 25], a1);
        atomicAdd(&sums[(v0 + 2) % 25], a2);
        atomicAdd(&sums[(v0 + 3) % 25], a3);
    }
    __syncthreads();
    if (tid < 25) m[n * 25 + tid] = sums[tid] * (1.0f / 768.0f);
}

// ---------------- K2: feat + global min/max ----------------
// grid 25 x 256 = 6400 threads, one per (n,w).
__global__ void k_feat(const float* __restrict__ m, float* __restrict__ feat,
                       unsigned int* __restrict__ mm) {
    const int idx = blockIdx.x * 256 + threadIdx.x;  // 0..6399
    const int n = idx / 25, w = idx % 25;
    const float* row = m + n * 25;
    const float mw = row[w];
    float s = 0.f;
    #pragma unroll
    for (int v = 0; v < 25; ++v) { float d = row[v] - mw; s += d * d; }
    const float f = sqrtf(s);
    feat[idx] = f;
    __shared__ unsigned int bmin, bmax;
    if (threadIdx.x == 0) { bmin = 0x7F800000u; bmax = 0u; }
    __syncthreads();
    atomicMin(&bmin, __float_as_uint(f));  // f >= 0 -> uint order == float order
    atomicMax(&bmax, __float_as_uint(f));
    __syncthreads();
    if (threadIdx.x == 0) { atomicMin(&mm[0], bmin); atomicMax(&mm[1], bmax); }
}

// ---------------- K3: distance matrix (fp16, unnormalized) ----------------
// block i = row, thread j = col. feat rows are L1/L2 resident (25.6 KB).
__global__ void k_dist(const float* __restrict__ feat, unsigned short* __restrict__ D16) {
    const int i = blockIdx.x;
    const int j = threadIdx.x;
    const float* fi = feat + i * 25;
    const float* fj = feat + j * 25;
    float s = 0.f;
    #pragma unroll
    for (int v = 0; v < 25; ++v) { float d = fi[v] - fj[v]; s += d * d; }
    const float dd = sqrtf(s);
    D16[i * 256 + j] = __half_as_ushort(__float2half(dd));
}

// ---------------- K4: Prim MST + structure-element layer ----------------
template <int CTRL>
__device__ __forceinline__ unsigned int dpp_min_step(unsigned int v) {
    unsigned int t = (unsigned int)__builtin_amdgcn_update_dpp(
        (int)0xFFFFFFFF, (int)v, CTRL, 0xF, 0xF, false);
    return (t < v) ? t : v;
}

__global__ void __launch_bounds__(256) k_mst(const unsigned short* __restrict__ D16g,
                                             const unsigned int* __restrict__ mm,
                                             const float* __restrict__ centres,
                                             const float* __restrict__ sharp,
                                             float* __restrict__ out) {
    __shared__ __align__(16) unsigned short Dl[65536];  // 128 KB (gfx950: 160 KB LDS)
    __shared__ float deaths[255];
    __shared__ float outpart[256];
    const int tid = threadIdx.x;

    // stage D16 global -> LDS (131072 B = 8192 uint4)
    {
        const uint4* src = reinterpret_cast<const uint4*>(D16g);
        uint4* dst = reinterpret_cast<uint4*>(Dl);
        #pragma unroll
        for (int it = 0; it < 32; ++it) {
            const int o = it * 256 + tid;
            dst[o] = src[o];
        }
    }
    __syncthreads();

    if (tid < 64) {  // Prim on wave 0; 4 nodes per lane; no barriers inside loop
        unsigned int key[4];
        #pragma unroll
        for (int s = 0; s < 4; ++s) {
            const int i = tid + 64 * s;
            const unsigned int h = Dl[i];  // row 0
            key[s] = (i == 0) ? 0xFFFFFFFFu : ((h << 16) | (unsigned int)i);
        }
        for (int it = 0; it < 255; ++it) {
            unsigned int v01 = (key[0] < key[1]) ? key[0] : key[1];
            unsigned int v23 = (key[2] < key[3]) ? key[2] : key[3];
            unsigned int v = (v01 < v23) ? v01 : v23;
            // wave64 min-reduce via DPP: row_shr 1/2/4/8, row_bcast15, row_bcast31
            v = dpp_min_step<0x111>(v);
            v = dpp_min_step<0x112>(v);
            v = dpp_min_step<0x114>(v);
            v = dpp_min_step<0x118>(v);
            v = dpp_min_step<0x142>(v);
            v = dpp_min_step<0x143>(v);
            const unsigned int gk = (unsigned int)__builtin_amdgcn_readlane((int)v, 63);
            const int j = (int)(gk & 0xFFFFu);
            if (tid == 0)
                deaths[it] = __half2float(__ushort_as_half((unsigned short)(gk >> 16)));
            const unsigned short* row = Dl + j * 256;
            #pragma unroll
            for (int s = 0; s < 4; ++s) {
                const int i = tid + 64 * s;
                if (i == j) {
                    key[s] = 0xFFFFFFFFu;  // entered tree; real keys are always < INF
                } else if (key[s] != 0xFFFFFFFFu) {
                    const unsigned int nk = (((unsigned int)row[i]) << 16) | (unsigned int)i;
                    key[s] = (nk < key[s]) ? nk : key[s];
                }
            }
        }
    }
    __syncthreads();

    // structure-element layer: out[k] = sum_i exp(-(c0^2 s0^2) - (d_i - c1)^2 s1^2)
    const float mn = __uint_as_float(mm[0]);
    const float mx = __uint_as_float(mm[1]);
    const float inv = 1.0f / (mx - mn);
    const int k = tid & 63;
    const int part = tid >> 6;
    const float c0 = centres[2 * k], c1 = centres[2 * k + 1];
    const float s0 = sharp[2 * k],   s1 = sharp[2 * k + 1];
    const float t0 = c0 * c0 * s0 * s0;
    const float s1sq = s1 * s1;
    float acc = 0.f;
    for (int i = part; i < 255; i += 4) {
        const float d = deaths[i] * inv - c1;
        acc += __expf(-(t0 + d * d * s1sq));
    }
    outpart[tid] = acc;
    __syncthreads();
    if (tid < 64)
        out[tid] = outpart[tid] + outpart[tid + 64] + outpart[tid + 128] + outpart[tid + 192];
}

extern "C" void kernel_launch(void* const* d_in, const int* in_sizes, int n_in,
                              void* d_out, int out_size, void* d_ws, size_t ws_size,
                              hipStream_t stream) {
    const float* x       = (const float*)d_in[0];
    const float* centres = (const float*)d_in[1];
    const float* sharp   = (const float*)d_in[2];
    float* out = (float*)d_out;
    char* ws = (char*)d_ws;
    float*          m    = (float*)(ws + WS_M);
    unsigned int*   mm   = (unsigned int*)(ws + WS_MM);
    float*          feat = (float*)(ws + WS_FEAT);
    unsigned short* D16  = (unsigned short*)(ws + WS_D16);

    k_mean<<<256, 256, 0, stream>>>(x, m, mm);
    k_feat<<<25, 256, 0, stream>>>(m, feat, mm);
    k_dist<<<256, 256, 0, stream>>>(feat, D16);
    k_mst<<<1, 256, 0, stream>>>(D16, mm, centres, sharp, out);
}

// Round 2
// 107.322 us; speedup vs baseline: 1.6298x; 1.6298x over previous
//
#include <hip/hip_runtime.h>
#include <hip/hip_fp16.h>

// Problem: Topo_60653528154131
//   x:[256,3,256,25] f32, centres:[64,2] f32, sharpness:[64,2] f32 -> out:[64] f32
//
// Pipeline (3 kernels):
//   K1 k_mean : m[n,v] = mean_{c,t} x[n,c,t,v]                (19.7 MB read, HBM-bound)
//   K2 k_dist : per block i: recompute feat from m (redundant, cheap),
//               D2_16[i,j] = fp16(||feat_i - feat_j||^2) -> global; block 0 -> min/max
//   K3 k_mst  : single-block parallel Boruvka on fp16 D2 keys (strict total order via
//               (w<<16)|canon(i,j)), deaths = sqrt(D2)*1/(max-min), structure layer.
//
// ws layout (needs 196608 B):
//   m   [6400] f32  @ 0
//   mm  [2]    u32  @ 25600   (min,max of feat as ordered-uint bits; feat>=0)
//   D16 [65536] u16 @ 65536   (fp16 bit patterns of D^2)

#define WS_M    0
#define WS_MM   25600
#define WS_D16  65536

// ---------------- K1: channel+time mean ----------------
__global__ void k_mean(const float* __restrict__ x, float* __restrict__ m) {
    const int n = blockIdx.x;
    const int tid = threadIdx.x;
    __shared__ float sums[25];
    if (tid < 25) sums[tid] = 0.0f;
    __syncthreads();
    if (tid < 200) {
        const float* base = x + (long)n * 19200 + 4 * tid;
        float a0 = 0.f, a1 = 0.f, a2 = 0.f, a3 = 0.f;
        #pragma unroll
        for (int i = 0; i < 24; ++i) {
            float4 v = *reinterpret_cast<const float4*>(base + 800 * i);
            a0 += v.x; a1 += v.y; a2 += v.z; a3 += v.w;
        }
        const int v0 = (4 * tid) % 25;
        atomicAdd(&sums[v0], a0);
        atomicAdd(&sums[(v0 + 1) % 25], a1);
        atomicAdd(&sums[(v0 + 2) % 25], a2);
        atomicAdd(&sums[(v0 + 3) % 25], a3);
    }
    __syncthreads();
    if (tid < 25) m[n * 25 + tid] = sums[tid] * (1.0f / 768.0f);
}

// ---------------- K2: feat (redundant per block) + D2 row + minmax (block 0) -------
__global__ void __launch_bounds__(256) k_dist(const float* __restrict__ m,
                                              unsigned short* __restrict__ D16,
                                              unsigned int* __restrict__ mm) {
    __shared__ float mS[6400];
    __shared__ float featS[6400];
    __shared__ unsigned int bmin, bmax;
    const int i = blockIdx.x;
    const int t = threadIdx.x;
    if (t == 0) { bmin = 0x7F800000u; bmax = 0u; }
    #pragma unroll
    for (int it = 0; it < 7; ++it) {  // stage m: 1600 float4
        int o = it * 256 + t;
        if (o < 1600) reinterpret_cast<float4*>(mS)[o] =
            reinterpret_cast<const float4*>(m)[o];
    }
    __syncthreads();
    // feat for node t: ||m[t,:] - m[t,w]|| = sqrt(S2 - 2 r_w S1 + 25 r_w^2)
    float r[25];
    #pragma unroll
    for (int v = 0; v < 25; ++v) r[v] = mS[t * 25 + v];
    float S1 = 0.f, S2 = 0.f;
    #pragma unroll
    for (int v = 0; v < 25; ++v) { S1 += r[v]; S2 += r[v] * r[v]; }
    float fmn = 1e30f, fmx = -1e30f;
    #pragma unroll
    for (int w = 0; w < 25; ++w) {
        float q = S2 - 2.f * r[w] * S1 + 25.f * r[w] * r[w];
        q = fmaxf(q, 0.f);
        float f = sqrtf(q);
        featS[t * 25 + w] = f;
        fmn = fminf(fmn, f); fmx = fmaxf(fmx, f);
    }
    if (i == 0) {  // only block 0 computes global min/max (all blocks have all feat)
        atomicMin(&bmin, __float_as_uint(fmn));
        atomicMax(&bmax, __float_as_uint(fmx));
    }
    __syncthreads();
    if (i == 0 && t == 0) { mm[0] = bmin; mm[1] = bmax; }
    // D2[i][t] from feat rows i (broadcast) and t (conflict-free, stride 25)
    float fi[25];
    #pragma unroll
    for (int v = 0; v < 25; ++v) fi[v] = featS[i * 25 + v];
    float s = 0.f;
    #pragma unroll
    for (int v = 0; v < 25; ++v) { float d = fi[v] - featS[t * 25 + v]; s += d * d; }
    D16[i * 256 + t] = __half_as_ushort(__float2half(s));
}

// ---------------- K3: single-block parallel Boruvka + structure layer -------------
// Row stride 264 halves (528 B): 528/16 = 33 (odd) -> lane-per-row b128 reads cover
// all 8 LDS b128 slots -> no bank conflicts (512 B stride would be 64-way).
#define DSTR 264

__global__ void __launch_bounds__(256) k_mst(const unsigned short* __restrict__ D16g,
                                             const unsigned int* __restrict__ mm,
                                             const float* __restrict__ centres,
                                             const float* __restrict__ sharp,
                                             float* __restrict__ out) {
    __shared__ __align__(16) unsigned short Dl[256 * DSTR];  // 132 KB
    __shared__ __align__(8) unsigned char compA[256];
    __shared__ unsigned char parent[256];
    __shared__ unsigned int compKey[256];
    __shared__ float deaths[256];
    __shared__ unsigned int dcount;
    __shared__ float outpart[256];
    const int tid = threadIdx.x;

    // stage D16 (dense 256x256) -> padded LDS rows
    {
        const uint4* src = reinterpret_cast<const uint4*>(D16g);
        #pragma unroll
        for (int it = 0; it < 32; ++it) {
            const int flat = it * 256 + tid;      // uint4 index, 0..8191
            const int r = flat >> 5, c = flat & 31;
            *reinterpret_cast<uint4*>(reinterpret_cast<char*>(Dl) + r * (DSTR * 2) + c * 16)
                = src[flat];
        }
    }
    compA[tid] = (unsigned char)tid;
    if (tid == 0) dcount = 0;
    __syncthreads();

    const int i = tid;
    const unsigned int ihi = (unsigned int)i << 8;
    const uint4* rowv = reinterpret_cast<const uint4*>(Dl + i * DSTR);
    const uint2* compv = reinterpret_cast<const uint2*>(compA);

    int nc = 256;
    while (nc > 1) {
        compKey[tid] = 0xFFFFFFFFu;
        __syncthreads();

        // ---- Phase A: every node scans its row for min outgoing edge key ----
        const unsigned int myComp = compA[i];
        unsigned int best = 0xFFFFFFFFu;
        #pragma unroll 4
        for (int c8 = 0; c8 < 32; ++c8) {
            const uint4 w4 = rowv[c8];
            const uint2 c2 = compv[c8];
            const int jb = c8 * 8;
            unsigned int wds[4] = {w4.x, w4.y, w4.z, w4.w};
            unsigned int cbs[2] = {c2.x, c2.y};
            #pragma unroll
            for (int u = 0; u < 8; ++u) {
                unsigned int w  = (wds[u >> 1] >> (16 * (u & 1))) & 0xFFFFu;
                unsigned int cj = (cbs[u >> 2] >> (8 * (u & 3))) & 0xFFu;
                unsigned int j = (unsigned int)(jb + u);
                unsigned int canon = (i < (int)j) ? (ihi | j) : ((j << 8) | (unsigned int)i);
                unsigned int key = (w << 16) | canon;
                key = (cj != myComp) ? key : 0xFFFFFFFFu;
                best = best < key ? best : key;
            }
        }
        if (best != 0xFFFFFFFFu) atomicMin(&compKey[myComp], best);
        __syncthreads();

        // ---- Phase B: hooking (thread = comp id) ----
        const unsigned int pk = compKey[tid];
        const bool isRoot = (compA[tid] == (unsigned char)tid);
        unsigned int par = (unsigned int)tid;
        if (isRoot && pk != 0xFFFFFFFFu) {
            const unsigned int canon = pk & 0xFFFFu;
            const unsigned int u = canon >> 8, v = canon & 0xFFu;
            const unsigned int cu = compA[u], cv = compA[v];
            par = (cu == (unsigned int)tid) ? cv : cu;
        }
        parent[tid] = (unsigned char)par;
        __syncthreads();

        // ---- Phase C: break mutual 2-cycles (same edge, strict total order) ----
        // lower id stays root (no death); partner hooks and records the edge once.
        if (isRoot && par != (unsigned int)tid) {
            if (parent[par] == (unsigned char)tid && (unsigned int)tid < par) {
                parent[tid] = (unsigned char)tid;
            } else {
                const unsigned int di = atomicAdd(&dcount, 1u);
                deaths[di] = sqrtf(__half2float(__ushort_as_half((unsigned short)(pk >> 16))));
            }
        }
        __syncthreads();

        // ---- Phase D: pointer jumping (depth <= 256 -> 8 jumps) ----
        #pragma unroll
        for (int s = 0; s < 8; ++s) {
            const unsigned char np = parent[parent[tid]];
            __syncthreads();
            parent[tid] = np;
            __syncthreads();
        }

        // ---- Phase E: relabel nodes; count remaining comps ----
        compA[tid] = parent[compA[tid]];
        nc = __syncthreads_count(compA[tid] == (unsigned char)tid);
    }

    // ---- structure-element layer: out[k] = sum_i exp(-c0^2 s0^2 - (d_i-c1)^2 s1^2)
    const float mn = __uint_as_float(mm[0]);
    const float mx = __uint_as_float(mm[1]);
    const float inv = 1.0f / (mx - mn);
    const int k = tid & 63;
    const int part = tid >> 6;
    const float c0 = centres[2 * k], c1 = centres[2 * k + 1];
    const float s0 = sharp[2 * k],   s1 = sharp[2 * k + 1];
    const float t0 = c0 * c0 * s0 * s0;
    const float s1sq = s1 * s1;
    float acc = 0.f;
    for (int idx = part; idx < 255; idx += 4) {
        const float d = deaths[idx] * inv - c1;
        acc += __expf(-(t0 + d * d * s1sq));
    }
    outpart[tid] = acc;
    __syncthreads();
    if (tid < 64)
        out[tid] = outpart[tid] + outpart[tid + 64] + outpart[tid + 128] + outpart[tid + 192];
}

extern "C" void kernel_launch(void* const* d_in, const int* in_sizes, int n_in,
                              void* d_out, int out_size, void* d_ws, size_t ws_size,
                              hipStream_t stream) {
    const float* x       = (const float*)d_in[0];
    const float* centres = (const float*)d_in[1];
    const float* sharp   = (const float*)d_in[2];
    float* out = (float*)d_out;
    char* ws = (char*)d_ws;
    float*          m   = (float*)(ws + WS_M);
    unsigned int*   mm  = (unsigned int*)(ws + WS_MM);
    unsigned short* D16 = (unsigned short*)(ws + WS_D16);

    k_mean<<<256, 256, 0, stream>>>(x, m);
    k_dist<<<256, 256, 0, stream>>>(m, D16, mm);
    k_mst<<<1, 256, 0, stream>>>(D16, mm, centres, sharp, out);
}

// Round 3
// 98.262 us; speedup vs baseline: 1.7801x; 1.0922x over previous
//
#include <hip/hip_runtime.h>
#include <hip/hip_fp16.h>

// Problem: Topo_60653528154131
//   x:[256,3,256,25] f32, centres:[64,2] f32, sharpness:[64,2] f32 -> out:[64] f32
//
// Pipeline (3 kernels):
//   K1 k_mean : m[n,v] = mean_{c,t} x[n,c,t,v]                (19.7 MB read, HBM-bound)
//   K2 k_dist : per block i: recompute feat from m (redundant, cheap),
//               D2_16[i,j] = fp16(||feat_i - feat_j||^2) -> global; block 0 -> min/max
//   K3 k_mst  : single-block 1024-thread parallel Boruvka on fp16 D2 keys
//               (strict total order via (w<<16)|canon(i,j)), deaths = sqrt(D2)/(max-min),
//               structure-element layer.
//
// ws layout (needs 196608 B):
//   m   [6400] f32  @ 0
//   mm  [2]    u32  @ 25600   (min,max of feat as ordered-uint bits; feat>=0)
//   D16 [65536] u16 @ 65536   (fp16 bit patterns of D^2)

#define WS_M    0
#define WS_MM   25600
#define WS_D16  65536

// ---------------- K1: channel+time mean ----------------
__global__ void k_mean(const float* __restrict__ x, float* __restrict__ m) {
    const int n = blockIdx.x;
    const int tid = threadIdx.x;
    __shared__ float sums[25];
    if (tid < 25) sums[tid] = 0.0f;
    __syncthreads();
    if (tid < 200) {
        const float* base = x + (long)n * 19200 + 4 * tid;
        float a0 = 0.f, a1 = 0.f, a2 = 0.f, a3 = 0.f;
        #pragma unroll
        for (int i = 0; i < 24; ++i) {
            float4 v = *reinterpret_cast<const float4*>(base + 800 * i);
            a0 += v.x; a1 += v.y; a2 += v.z; a3 += v.w;
        }
        const int v0 = (4 * tid) % 25;
        atomicAdd(&sums[v0], a0);
        atomicAdd(&sums[(v0 + 1) % 25], a1);
        atomicAdd(&sums[(v0 + 2) % 25], a2);
        atomicAdd(&sums[(v0 + 3) % 25], a3);
    }
    __syncthreads();
    if (tid < 25) m[n * 25 + tid] = sums[tid] * (1.0f / 768.0f);
}

// ---------------- K2: feat (redundant per block) + D2 row + minmax (block 0) -------
__global__ void __launch_bounds__(256) k_dist(const float* __restrict__ m,
                                              unsigned short* __restrict__ D16,
                                              unsigned int* __restrict__ mm) {
    __shared__ float mS[6400];
    __shared__ float featS[6400];
    __shared__ unsigned int bmin, bmax;
    const int i = blockIdx.x;
    const int t = threadIdx.x;
    if (t == 0) { bmin = 0x7F800000u; bmax = 0u; }
    #pragma unroll
    for (int it = 0; it < 7; ++it) {  // stage m: 1600 float4
        int o = it * 256 + t;
        if (o < 1600) reinterpret_cast<float4*>(mS)[o] =
            reinterpret_cast<const float4*>(m)[o];
    }
    __syncthreads();
    // feat for node t: ||m[t,:] - m[t,w]|| = sqrt(S2 - 2 r_w S1 + 25 r_w^2)
    float r[25];
    #pragma unroll
    for (int v = 0; v < 25; ++v) r[v] = mS[t * 25 + v];
    float S1 = 0.f, S2 = 0.f;
    #pragma unroll
    for (int v = 0; v < 25; ++v) { S1 += r[v]; S2 += r[v] * r[v]; }
    float fmn = 1e30f, fmx = -1e30f;
    #pragma unroll
    for (int w = 0; w < 25; ++w) {
        float q = S2 - 2.f * r[w] * S1 + 25.f * r[w] * r[w];
        q = fmaxf(q, 0.f);
        float f = sqrtf(q);
        featS[t * 25 + w] = f;
        fmn = fminf(fmn, f); fmx = fmaxf(fmx, f);
    }
    if (i == 0) {  // only block 0 computes global min/max (all blocks have all feat)
        atomicMin(&bmin, __float_as_uint(fmn));
        atomicMax(&bmax, __float_as_uint(fmx));
    }
    __syncthreads();
    if (i == 0 && t == 0) { mm[0] = bmin; mm[1] = bmax; }
    // D2[i][t] from feat rows i (broadcast) and t (conflict-free, stride 25)
    float fi[25];
    #pragma unroll
    for (int v = 0; v < 25; ++v) fi[v] = featS[i * 25 + v];
    float s = 0.f;
    #pragma unroll
    for (int v = 0; v < 25; ++v) { float d = fi[v] - featS[t * 25 + v]; s += d * d; }
    D16[i * 256 + t] = __half_as_ushort(__float2half(s));
}

// ---------------- K3: single-block 1024-thread Boruvka + structure layer ----------
// Row stride 264 halves (132 words): within a wave (64 consecutive rows, uniform q)
// every consecutive-8-lane group of a b128 read covers all 32 banks -> conflict-free.
#define DSTR 264

__global__ void __launch_bounds__(1024) k_mst(const unsigned short* __restrict__ D16g,
                                              const unsigned int* __restrict__ mm,
                                              const float* __restrict__ centres,
                                              const float* __restrict__ sharp,
                                              float* __restrict__ out) {
    __shared__ __align__(16) unsigned short Dl[256 * DSTR];  // 132 KB
    __shared__ __align__(8) unsigned char compA[256];
    __shared__ unsigned char parent[256];
    __shared__ unsigned int rowKey[256];
    __shared__ unsigned int compKey[256];
    __shared__ float deaths[256];
    __shared__ unsigned int dcount;
    __shared__ float outpart[1024];
    const int tid = threadIdx.x;

    // stage D16 (dense 256x256) -> padded LDS rows: 8192 uint4, 8 per thread
    {
        const uint4* src = reinterpret_cast<const uint4*>(D16g);
        #pragma unroll
        for (int it = 0; it < 8; ++it) {
            const int flat = it * 1024 + tid;     // uint4 index, 0..8191
            const int rr = flat >> 5, cc = flat & 31;
            *reinterpret_cast<uint4*>(reinterpret_cast<char*>(Dl) + rr * (DSTR * 2) + cc * 16)
                = src[flat];
        }
    }
    if (tid < 256) compA[tid] = (unsigned char)tid;
    if (tid == 0) dcount = 0;
    __syncthreads();

    const int r = tid & 255;          // my row (node)
    const int q = tid >> 8;           // my quarter (j in [64q, 64q+64))
    const int jb0 = q * 64;
    const uint4* rowq = reinterpret_cast<const uint4*>(
        reinterpret_cast<const char*>(Dl) + r * (DSTR * 2) + jb0 * 2);
    const uint2* compv = reinterpret_cast<const uint2*>(compA);

    // precompute packed canonical edge ids for my 64 columns (round-invariant)
    unsigned int cano[32];
    #pragma unroll
    for (int t2 = 0; t2 < 32; ++t2) {
        const int j0 = jb0 + 2 * t2, j1 = j0 + 1;
        const unsigned int c0 = (r < j0) ? (((unsigned)r << 8) | j0) : (((unsigned)j0 << 8) | r);
        const unsigned int c1 = (r < j1) ? (((unsigned)r << 8) | j1) : (((unsigned)j1 << 8) | r);
        cano[t2] = c0 | (c1 << 16);
    }

    int nc = 256;
    while (nc > 1) {
        if (tid < 256) { rowKey[tid] = 0xFFFFFFFFu; compKey[tid] = 0xFFFFFFFFu; }
        __syncthreads();

        // ---- Phase A: scan my 64 edges for min outgoing key ----
        const unsigned int myComp = compA[r];
        unsigned int best = 0xFFFFFFFFu;
        #pragma unroll
        for (int c8 = 0; c8 < 8; ++c8) {
            const uint4 w4 = rowq[c8];
            const uint2 c2 = compv[q * 8 + c8];   // wave-uniform -> broadcast
            const unsigned int wds[4] = {w4.x, w4.y, w4.z, w4.w};
            const unsigned int cbs[2] = {c2.x, c2.y};
            #pragma unroll
            for (int p = 0; p < 4; ++p) {         // edge pairs
                const unsigned int ww = wds[p];
                const unsigned int cp = cano[c8 * 4 + p];
                unsigned int k0 = (ww << 16) | (cp & 0xFFFFu);
                unsigned int k1 = (ww & 0xFFFF0000u) | (cp >> 16);
                const unsigned int cj0 = (cbs[p >> 1] >> (16 * (p & 1))) & 0xFFu;
                const unsigned int cj1 = (cbs[p >> 1] >> (16 * (p & 1) + 8)) & 0xFFu;
                k0 = (cj0 != myComp) ? k0 : 0xFFFFFFFFu;
                k1 = (cj1 != myComp) ? k1 : 0xFFFFFFFFu;
                best = best < k0 ? best : k0;
                best = best < k1 ? best : k1;
            }
        }
        if (best != 0xFFFFFFFFu) atomicMin(&rowKey[r], best);  // 4-way contention
        __syncthreads();
        if (tid < 256) {
            const unsigned int rk = rowKey[tid];
            if (rk != 0xFFFFFFFFu) atomicMin(&compKey[compA[tid]], rk);
        }
        __syncthreads();

        // ---- Phase B: hooking (thread = comp id) ----
        unsigned int pk = 0xFFFFFFFFu;
        bool isRoot = false;
        unsigned int par = (unsigned int)tid;
        if (tid < 256) {
            pk = compKey[tid];
            isRoot = (compA[tid] == (unsigned char)tid);
            if (isRoot && pk != 0xFFFFFFFFu) {
                const unsigned int canon = pk & 0xFFFFu;
                const unsigned int u = canon >> 8, v = canon & 0xFFu;
                const unsigned int cu = compA[u], cv = compA[v];
                par = (cu == (unsigned int)tid) ? cv : cu;
            }
            parent[tid] = (unsigned char)par;
        }
        __syncthreads();

        // ---- Phase C: break mutual 2-cycles (same edge; total order => only 2-cycles)
        if (tid < 256 && isRoot && par != (unsigned int)tid) {
            if (parent[par] == (unsigned char)tid && (unsigned int)tid < par) {
                parent[tid] = (unsigned char)tid;   // winner stays root, no death
            } else {
                const unsigned int di = atomicAdd(&dcount, 1u);
                deaths[di] = sqrtf(__half2float(__ushort_as_half((unsigned short)(pk >> 16))));
            }
        }
        __syncthreads();

        // ---- Phase D: convergence-checked pointer jumping ----
        for (;;) {
            unsigned char p0 = 0, np = 0;
            if (tid < 256) { p0 = parent[tid]; np = parent[p0]; }
            const int cnt = __syncthreads_count(tid < 256 && np != p0);
            if (tid < 256) parent[tid] = np;
            __syncthreads();
            if (cnt == 0) break;
        }

        // ---- Phase E: relabel nodes; count remaining comps ----
        if (tid < 256) compA[tid] = parent[compA[tid]];
        nc = __syncthreads_count(tid < 256 && compA[tid] == (unsigned char)tid);
    }

    // ---- structure-element layer: out[k] = sum_i exp(-c0^2 s0^2 - (d_i-c1)^2 s1^2)
    const float mn = __uint_as_float(mm[0]);
    const float mx = __uint_as_float(mm[1]);
    const float inv = 1.0f / (mx - mn);
    const int k = tid & 63;
    const int part = tid >> 6;  // 16 partials per k
    const float c0 = centres[2 * k], c1 = centres[2 * k + 1];
    const float s0 = sharp[2 * k],   s1 = sharp[2 * k + 1];
    const float t0 = c0 * c0 * s0 * s0;
    const float s1sq = s1 * s1;
    float acc = 0.f;
    for (int idx = part; idx < 255; idx += 16) {
        const float d = deaths[idx] * inv - c1;
        acc += __expf(-(t0 + d * d * s1sq));
    }
    outpart[tid] = acc;
    __syncthreads();
    if (tid < 64) {
        float s = 0.f;
        #pragma unroll
        for (int pp = 0; pp < 16; ++pp) s += outpart[tid + 64 * pp];
        out[tid] = s;
    }
}

extern "C" void kernel_launch(void* const* d_in, const int* in_sizes, int n_in,
                              void* d_out, int out_size, void* d_ws, size_t ws_size,
                              hipStream_t stream) {
    const float* x       = (const float*)d_in[0];
    const float* centres = (const float*)d_in[1];
    const float* sharp   = (const float*)d_in[2];
    float* out = (float*)d_out;
    char* ws = (char*)d_ws;
    float*          m   = (float*)(ws + WS_M);
    unsigned int*   mm  = (unsigned int*)(ws + WS_MM);
    unsigned short* D16 = (unsigned short*)(ws + WS_D16);

    k_mean<<<256, 256, 0, stream>>>(x, m);
    k_dist<<<256, 256, 0, stream>>>(m, D16, mm);
    k_mst<<<1, 1024, 0, stream>>>(D16, mm, centres, sharp, out);
}

// Round 4
// 96.030 us; speedup vs baseline: 1.8215x; 1.0232x over previous
//
#include <hip/hip_runtime.h>
#include <hip/hip_fp16.h>

// Problem: Topo_60653528154131
//   x:[256,3,256,25] f32, centres:[64,2] f32, sharpness:[64,2] f32 -> out:[64] f32
//
// Pipeline (3 kernels):
//   K1 k_mean : m[n,v] = mean_{c,t} x[n,c,t,v]                (19.7 MB read, HBM-bound)
//   K2 k_dist : per block i: feat (redundant recompute from m), D2 row i -> global,
//               row-min edge key (DPP reduce) -> rowKeyG[i], block 0 -> feat min/max
//   K3 k_mst  : Boruvka WITH EXPLICIT CONTRACTION. Round 1 hooking uses precomputed
//               rowKeyG; contraction reads D16 from global (L2-hot) and atomicMins
//               packed (w<<16|canon) u32 cells into LDS; later rounds scan/contract
//               n^2 <= 16K cells (ping-pong LDS buffers). Wave0 does hook/2-cycle/
//               pointer-jump/renumber barrier-free. deaths = sqrt(D2)/(max-min),
//               then structure-element layer.
//
// ws layout:
//   m       [6400] f32 @ 0
//   mm      [2]    u32 @ 25600   (min,max of feat as ordered-uint bits; feat>=0)
//   rowKeyG [256]  u32 @ 28672
//   D16     [65536]u16 @ 65536   (fp16 bit patterns of D^2)

#define WS_M    0
#define WS_MM   25600
#define WS_RK   28672
#define WS_D16  65536

#define INF32 0xFFFFFFFFu

// ---------------- K1: channel+time mean ----------------
__global__ void k_mean(const float* __restrict__ x, float* __restrict__ m) {
    const int n = blockIdx.x;
    const int tid = threadIdx.x;
    __shared__ float sums[25];
    if (tid < 25) sums[tid] = 0.0f;
    __syncthreads();
    if (tid < 200) {
        const float* base = x + (long)n * 19200 + 4 * tid;
        float a0 = 0.f, a1 = 0.f, a2 = 0.f, a3 = 0.f;
        #pragma unroll
        for (int i = 0; i < 24; ++i) {
            float4 v = *reinterpret_cast<const float4*>(base + 800 * i);
            a0 += v.x; a1 += v.y; a2 += v.z; a3 += v.w;
        }
        const int v0 = (4 * tid) % 25;
        atomicAdd(&sums[v0], a0);
        atomicAdd(&sums[(v0 + 1) % 25], a1);
        atomicAdd(&sums[(v0 + 2) % 25], a2);
        atomicAdd(&sums[(v0 + 3) % 25], a3);
    }
    __syncthreads();
    if (tid < 25) m[n * 25 + tid] = sums[tid] * (1.0f / 768.0f);
}

// wave64 min-reduce step via DPP (R1-verified): invalid lanes keep old=INF
template <int CTRL>
__device__ __forceinline__ unsigned int dpp_min_step(unsigned int v) {
    unsigned int t = (unsigned int)__builtin_amdgcn_update_dpp(
        (int)0xFFFFFFFF, (int)v, CTRL, 0xF, 0xF, false);
    return (t < v) ? t : v;
}

// ---------------- K2: feat + D2 row + row-min key + minmax ----------------
__global__ void __launch_bounds__(256) k_dist(const float* __restrict__ m,
                                              unsigned short* __restrict__ D16,
                                              unsigned int* __restrict__ rowKeyG,
                                              unsigned int* __restrict__ mm) {
    __shared__ float mS[6400];
    __shared__ float featS[6400];
    __shared__ unsigned int bmin, bmax;
    __shared__ unsigned int wred[4];
    const int i = blockIdx.x;
    const int t = threadIdx.x;
    if (t == 0) { bmin = 0x7F800000u; bmax = 0u; }
    #pragma unroll
    for (int it = 0; it < 7; ++it) {  // stage m: 1600 float4
        int o = it * 256 + t;
        if (o < 1600) reinterpret_cast<float4*>(mS)[o] =
            reinterpret_cast<const float4*>(m)[o];
    }
    __syncthreads();
    // feat for node t: ||m[t,:] - m[t,w]|| = sqrt(S2 - 2 r_w S1 + 25 r_w^2)
    float r[25];
    #pragma unroll
    for (int v = 0; v < 25; ++v) r[v] = mS[t * 25 + v];
    float S1 = 0.f, S2 = 0.f;
    #pragma unroll
    for (int v = 0; v < 25; ++v) { S1 += r[v]; S2 += r[v] * r[v]; }
    float fmn = 1e30f, fmx = -1e30f;
    #pragma unroll
    for (int w = 0; w < 25; ++w) {
        float q = S2 - 2.f * r[w] * S1 + 25.f * r[w] * r[w];
        q = fmaxf(q, 0.f);
        float f = sqrtf(q);
        featS[t * 25 + w] = f;
        fmn = fminf(fmn, f); fmx = fmaxf(fmx, f);
    }
    if (i == 0) {  // only block 0 publishes global min/max (all blocks have all feat)
        atomicMin(&bmin, __float_as_uint(fmn));
        atomicMax(&bmax, __float_as_uint(fmx));
    }
    __syncthreads();
    if (i == 0 && t == 0) { mm[0] = bmin; mm[1] = bmax; }
    // D2[i][t]
    float fi[25];
    #pragma unroll
    for (int v = 0; v < 25; ++v) fi[v] = featS[i * 25 + v];
    float s = 0.f;
    #pragma unroll
    for (int v = 0; v < 25; ++v) { float d = fi[v] - featS[t * 25 + v]; s += d * d; }
    const unsigned int w16 = (unsigned int)__half_as_ushort(__float2half(s));
    D16[i * 256 + t] = (unsigned short)w16;
    // row-min edge key for Boruvka round 1 (exclude diagonal)
    const unsigned int lo = (i < t) ? i : t, hi = (i < t) ? t : i;
    unsigned int key = (t == i) ? INF32 : ((w16 << 16) | (lo << 8) | hi);
    key = dpp_min_step<0x111>(key);
    key = dpp_min_step<0x112>(key);
    key = dpp_min_step<0x114>(key);
    key = dpp_min_step<0x118>(key);
    key = dpp_min_step<0x142>(key);
    key = dpp_min_step<0x143>(key);
    if ((t & 63) == 63) wred[t >> 6] = key;  // lane 63 holds wave min
    __syncthreads();
    if (t == 0) {
        unsigned int b0 = wred[0] < wred[1] ? wred[0] : wred[1];
        unsigned int b1 = wred[2] < wred[3] ? wred[2] : wred[3];
        rowKeyG[i] = b0 < b1 ? b0 : b1;
    }
}

// ---------------- K3: contracting Boruvka + structure layer ----------------
#define SA 132   // u32 stride, buffer A (cap 128 rows)
#define SB 68    // u32 stride, buffer B (cap 64 rows)
#define OFF_B (128 * SA)

// wave0-only: hook -> 2-cycle break (+deaths) -> pointer jump -> dense renumber.
// Runs on lanes of wave 0 only; no __syncthreads inside (in-wave LDS ordering).
__device__ __forceinline__ void wave0_phase(int n, int lane,
        unsigned int* rowKeyS, unsigned char* parentS, unsigned char* newidS,
        unsigned char* cmapS, float* deaths, unsigned int* ncS, unsigned int* dcS) {
    unsigned int par[4];
    #pragma unroll
    for (int s = 0; s < 4; ++s) {         // hook
        const int i = lane + 64 * s;
        if (i < n) {
            const unsigned int rk = rowKeyS[i];
            const unsigned int u = (rk >> 8) & 0xFFu, v = rk & 0xFFu;
            unsigned int p = (u == (unsigned int)i) ? v : u;
            if (rk == INF32) p = (unsigned int)i;  // safety (n>=2 complete graph: unused)
            par[s] = p;
            parentS[i] = (unsigned char)p;
        }
    }
    #pragma unroll
    for (int s = 0; s < 4; ++s) {         // break mutual 2-cycles; record deaths
        const int i = lane + 64 * s;
        if (i < n) {
            const unsigned int p = par[s];
            if (p != (unsigned int)i) {
                const unsigned int mp = parentS[p];
                if (mp == (unsigned int)i && (unsigned int)i < p) {
                    parentS[i] = (unsigned char)i;   // winner stays root, no death
                } else {
                    const unsigned int d = atomicAdd(dcS, 1u);
                    const unsigned int rk = rowKeyS[i];
                    deaths[d] = sqrtf(__half2float(__ushort_as_half(
                        (unsigned short)(rk >> 16))));
                }
            }
        }
    }
    for (;;) {                            // async pointer jumping (ancestor-monotone)
        bool ch = false;
        #pragma unroll
        for (int s = 0; s < 4; ++s) {
            const int i = lane + 64 * s;
            if (i < n) {
                const unsigned char p0 = parentS[i];
                const unsigned char np = parentS[p0];
                if (np != p0) { ch = true; parentS[i] = np; }
            }
        }
        if (__ballot(ch) == 0ull) break;
    }
    #pragma unroll
    for (int s = 0; s < 4; ++s) {         // dense renumber of roots
        const int i = lane + 64 * s;
        if (i < n && parentS[i] == (unsigned char)i)
            newidS[i] = (unsigned char)atomicAdd(ncS, 1u);
    }
    #pragma unroll
    for (int s = 0; s < 4; ++s) {         // node -> new comp id
        const int i = lane + 64 * s;
        if (i < n) cmapS[i] = newidS[parentS[i]];
    }
}

__global__ void __launch_bounds__(1024) k_mst(const unsigned short* __restrict__ D16g,
                                              const unsigned int* __restrict__ rowKeyG,
                                              const unsigned int* __restrict__ mm,
                                              const float* __restrict__ centres,
                                              const float* __restrict__ sharp,
                                              float* __restrict__ out) {
    __shared__ unsigned int Mb[128 * SA + 64 * SB];   // 85 KB: ping-pong A|B
    __shared__ unsigned int rowKeyS[256];
    __shared__ unsigned char parentS[256], newidS[256];
    __shared__ __align__(8) unsigned char cmapS[256];
    __shared__ unsigned int ncS, dcS;
    __shared__ float deaths[256];
    __shared__ float outpart[1024];
    const int tid = threadIdx.x;

    // ---- round 1: hooking from precomputed row keys ----
    if (tid < 256) rowKeyS[tid] = rowKeyG[tid];
    if (tid == 0) { ncS = 0; dcS = 0; }
    __syncthreads();
    if (tid < 64)
        wave0_phase(256, tid, rowKeyS, parentS, newidS, cmapS, deaths, &ncS, &dcS);
    __syncthreads();
    int n = (int)ncS;

    // ---- round 1 contraction: global D16 -> buffer A (keys (w<<16)|canon(new ids))
    if (n > 1) {
        for (int w = tid; w < n * SA; w += 1024) Mb[w] = INF32;
        __syncthreads();
        const int r = tid & 255, q = tid >> 8, jb0 = q * 64;
        const unsigned int cr = cmapS[r];
        const uint4* src = reinterpret_cast<const uint4*>(D16g) + r * 32 + q * 8;
        const uint2* cmv = reinterpret_cast<const uint2*>(cmapS);
        #pragma unroll
        for (int c8 = 0; c8 < 8; ++c8) {
            const uint4 w4 = src[c8];
            const uint2 c2 = cmv[q * 8 + c8];
            const unsigned int wds[4] = {w4.x, w4.y, w4.z, w4.w};
            const unsigned int cbs[2] = {c2.x, c2.y};
            #pragma unroll
            for (int u = 0; u < 8; ++u) {
                const unsigned int cj = (cbs[u >> 2] >> (8 * (u & 3))) & 0xFFu;
                if (cj != cr) {
                    const unsigned int w16 = (wds[u >> 1] >> (16 * (u & 1))) & 0xFFFFu;
                    const unsigned int lo = cr < cj ? cr : cj;
                    const unsigned int hi = cr < cj ? cj : cr;
                    atomicMin(&Mb[cr * SA + cj], (w16 << 16) | (lo << 8) | hi);
                }
            }
        }
        __syncthreads();
    }

    // ---- rounds 2+: scan / hook / contract on shrinking matrices ----
    int srcOff = 0, srcStr = SA, dstOff = OFF_B, dstStr = SB;
    while (n > 1) {
        if (tid < n) rowKeyS[tid] = INF32;
        if (tid == 0) ncS = 0;
        __syncthreads();
        if (tid < 8 * n) {                 // scan: 8 threads per row
            const int a = tid >> 3, sub = tid & 7;
            const unsigned int* row = &Mb[srcOff + a * srcStr];
            unsigned int best = INF32;
            for (int b = sub; b < n; b += 8) {
                const unsigned int v = row[b];
                best = v < best ? v : best;   // diagonal/unwritten stay INF
            }
            if (best != INF32) atomicMin(&rowKeyS[a], best);
        }
        __syncthreads();
        if (tid < 64)
            wave0_phase(n, tid, rowKeyS, parentS, newidS, cmapS, deaths, &ncS, &dcS);
        __syncthreads();
        const int nc = (int)ncS;
        if (nc > 1) {                      // contract src -> dst (disjoint buffers)
            for (int w = tid; w < nc * dstStr; w += 1024) Mb[dstOff + w] = INF32;
            __syncthreads();
            if (tid < 8 * n) {
                const int a = tid >> 3, sub = tid & 7;
                const unsigned int ca = cmapS[a];
                const unsigned int* row = &Mb[srcOff + a * srcStr];
                for (int b = sub; b < n; b += 8) {
                    const unsigned int cb = cmapS[b];
                    const unsigned int v = row[b];
                    if (ca != cb && v != INF32) {
                        const unsigned int lo = ca < cb ? ca : cb;
                        const unsigned int hi = ca < cb ? cb : ca;
                        atomicMin(&Mb[dstOff + ca * dstStr + cb],
                                  (v & 0xFFFF0000u) | (lo << 8) | hi);
                    }
                }
            }
            __syncthreads();
        }
        const int t1 = srcOff; srcOff = dstOff; dstOff = t1;
        const int t2 = srcStr; srcStr = dstStr; dstStr = t2;
        n = nc;
    }

    // ---- structure-element layer: out[k] = sum_i exp(-c0^2 s0^2 - (d_i-c1)^2 s1^2)
    const float mn = __uint_as_float(mm[0]);
    const float mx = __uint_as_float(mm[1]);
    const float inv = 1.0f / (mx - mn);
    const int k = tid & 63;
    const int part = tid >> 6;  // 16 partials per k
    const float c0 = centres[2 * k], c1 = centres[2 * k + 1];
    const float s0 = sharp[2 * k],   s1 = sharp[2 * k + 1];
    const float t0 = c0 * c0 * s0 * s0;
    const float s1sq = s1 * s1;
    float acc = 0.f;
    for (int idx = part; idx < 255; idx += 16) {
        const float d = deaths[idx] * inv - c1;
        acc += __expf(-(t0 + d * d * s1sq));
    }
    outpart[tid] = acc;
    __syncthreads();
    if (tid < 64) {
        float s = 0.f;
        #pragma unroll
        for (int pp = 0; pp < 16; ++pp) s += outpart[tid + 64 * pp];
        out[tid] = s;
    }
}

extern "C" void kernel_launch(void* const* d_in, const int* in_sizes, int n_in,
                              void* d_out, int out_size, void* d_ws, size_t ws_size,
                              hipStream_t stream) {
    const float* x       = (const float*)d_in[0];
    const float* centres = (const float*)d_in[1];
    const float* sharp   = (const float*)d_in[2];
    float* out = (float*)d_out;
    char* ws = (char*)d_ws;
    float*          m   = (float*)(ws + WS_M);
    unsigned int*   mm  = (unsigned int*)(ws + WS_MM);
    unsigned int*   rk  = (unsigned int*)(ws + WS_RK);
    unsigned short* D16 = (unsigned short*)(ws + WS_D16);

    k_mean<<<256, 256, 0, stream>>>(x, m);
    k_dist<<<256, 256, 0, stream>>>(m, D16, rk, mm);
    k_mst<<<1, 1024, 0, stream>>>(D16, rk, mm, centres, sharp, out);
}

// Round 6
// 93.644 us; speedup vs baseline: 1.8679x; 1.0255x over previous
//
#include <hip/hip_runtime.h>
#include <hip/hip_fp16.h>

// Problem: Topo_60653528154131
//   x:[256,3,256,25] f32, centres:[64,2] f32, sharpness:[64,2] f32 -> out:[64] f32
//
// Pipeline (4 kernels):
//   K1 k_mean     : m[n,v] = mean_{c,t} x  (HBM-bound) + INF-init of Mp region
//   K2 k_dist     : feat (redundant per block), D2 row -> D16, row-min key -> rowKeyG,
//                   block 0 -> feat min/max
//   K3 k_contract : 256 blocks. Each block redundantly+deterministically replays
//                   Boruvka round-1 hooking from rowKeyG (ballot-rank renumber ->
//                   identical cmap in every block), then folds ITS row of D16 into
//                   Mp[ca][cb] via GLOBAL atomicMin (storm distributed over 256 CUs).
//   K4 k_mst      : 1 block. Re-hook round 1 from rowKeyG (records deaths), copy Mp
//                   (n1<=128) to LDS, Boruvka rounds 2+ on shrinking matrices,
//                   deaths = sqrt(D2)/(max-min), structure-element layer.
//
// ws layout:
//   m       [6400]  f32 @ 0
//   mm      [2]     u32 @ 25600
//   rowKeyG [256]   u32 @ 28672
//   D16     [65536] u16 @ 65536    (fp16 bits of D^2)
//   Mp      [128*132] u32 @ 196608 (round-1 contracted matrix, stride 132)

#define WS_M    0
#define WS_MM   25600
#define WS_RK   28672
#define WS_D16  65536
#define WS_MP   196608

#define INF32 0xFFFFFFFFu
#define MPSTR 132

// ---------------- K1: channel+time mean + Mp INF-init ----------------
__global__ void k_mean(const float* __restrict__ x, float* __restrict__ m,
                       unsigned int* __restrict__ Mp) {
    const int n = blockIdx.x;
    const int tid = threadIdx.x;
    if (tid < 66) Mp[n * 66 + tid] = INF32;   // 256*66 = 16896 = 128*132 exactly
    __shared__ float sums[25];
    if (tid < 25) sums[tid] = 0.0f;
    __syncthreads();
    if (tid < 200) {
        const float* base = x + (long)n * 19200 + 4 * tid;
        float a0 = 0.f, a1 = 0.f, a2 = 0.f, a3 = 0.f;
        #pragma unroll
        for (int i = 0; i < 24; ++i) {
            float4 v = *reinterpret_cast<const float4*>(base + 800 * i);
            a0 += v.x; a1 += v.y; a2 += v.z; a3 += v.w;
        }
        const int v0 = (4 * tid) % 25;
        atomicAdd(&sums[v0], a0);
        atomicAdd(&sums[(v0 + 1) % 25], a1);
        atomicAdd(&sums[(v0 + 2) % 25], a2);
        atomicAdd(&sums[(v0 + 3) % 25], a3);
    }
    __syncthreads();
    if (tid < 25) m[n * 25 + tid] = sums[tid] * (1.0f / 768.0f);
}

// wave64 min-reduce step via DPP: invalid lanes keep old=INF
template <int CTRL>
__device__ __forceinline__ unsigned int dpp_min_step(unsigned int v) {
    unsigned int t = (unsigned int)__builtin_amdgcn_update_dpp(
        (int)0xFFFFFFFF, (int)v, CTRL, 0xF, 0xF, false);
    return (t < v) ? t : v;
}

// ---------------- K2: feat + D2 row + row-min key + minmax ----------------
__global__ void __launch_bounds__(256) k_dist(const float* __restrict__ m,
                                              unsigned short* __restrict__ D16,
                                              unsigned int* __restrict__ rowKeyG,
                                              unsigned int* __restrict__ mm) {
    __shared__ float mS[6400];
    __shared__ float featS[6400];
    __shared__ unsigned int bmin, bmax;
    __shared__ unsigned int wred[4];
    const int i = blockIdx.x;
    const int t = threadIdx.x;
    if (t == 0) { bmin = 0x7F800000u; bmax = 0u; }
    #pragma unroll
    for (int it = 0; it < 7; ++it) {
        int o = it * 256 + t;
        if (o < 1600) reinterpret_cast<float4*>(mS)[o] =
            reinterpret_cast<const float4*>(m)[o];
    }
    __syncthreads();
    float r[25];
    #pragma unroll
    for (int v = 0; v < 25; ++v) r[v] = mS[t * 25 + v];
    float S1 = 0.f, S2 = 0.f;
    #pragma unroll
    for (int v = 0; v < 25; ++v) { S1 += r[v]; S2 += r[v] * r[v]; }
    float fmn = 1e30f, fmx = -1e30f;
    #pragma unroll
    for (int w = 0; w < 25; ++w) {
        float q = S2 - 2.f * r[w] * S1 + 25.f * r[w] * r[w];
        q = fmaxf(q, 0.f);
        float f = sqrtf(q);
        featS[t * 25 + w] = f;
        fmn = fminf(fmn, f); fmx = fmaxf(fmx, f);
    }
    if (i == 0) {
        atomicMin(&bmin, __float_as_uint(fmn));
        atomicMax(&bmax, __float_as_uint(fmx));
    }
    __syncthreads();
    if (i == 0 && t == 0) { mm[0] = bmin; mm[1] = bmax; }
    float fi[25];
    #pragma unroll
    for (int v = 0; v < 25; ++v) fi[v] = featS[i * 25 + v];
    float s = 0.f;
    #pragma unroll
    for (int v = 0; v < 25; ++v) { float d = fi[v] - featS[t * 25 + v]; s += d * d; }
    const unsigned int w16 = (unsigned int)__half_as_ushort(__float2half(s));
    D16[i * 256 + t] = (unsigned short)w16;
    const unsigned int lo = (i < t) ? i : t, hi = (i < t) ? t : i;
    unsigned int key = (t == i) ? INF32 : ((w16 << 16) | (lo << 8) | hi);
    key = dpp_min_step<0x111>(key);
    key = dpp_min_step<0x112>(key);
    key = dpp_min_step<0x114>(key);
    key = dpp_min_step<0x118>(key);
    key = dpp_min_step<0x142>(key);
    key = dpp_min_step<0x143>(key);
    if ((t & 63) == 63) wred[t >> 6] = key;
    __syncthreads();
    if (t == 0) {
        unsigned int b0 = wred[0] < wred[1] ? wred[0] : wred[1];
        unsigned int b1 = wred[2] < wred[3] ? wred[2] : wred[3];
        rowKeyG[i] = b0 < b1 ? b0 : b1;
    }
}

// ---------------- wave0 Boruvka phase (DETERMINISTIC) ----------------
// hook -> 2-cycle break (optional death record) -> async pointer jump ->
// BALLOT-RANK renumber (deterministic: identical result in every block).
// Runs on lanes of wave 0 only; no __syncthreads inside.
template <bool RECORD>
__device__ __forceinline__ void wave0_phase(int n, int lane,
        unsigned int* rowKeyS, unsigned char* parentS, unsigned char* newidS,
        unsigned char* cmapS, float* deaths, unsigned int* ncS, unsigned int* dcS) {
    unsigned int par[4];
    #pragma unroll
    for (int s = 0; s < 4; ++s) {         // hook
        const int i = lane + 64 * s;
        if (i < n) {
            const unsigned int rk = rowKeyS[i];
            const unsigned int u = (rk >> 8) & 0xFFu, v = rk & 0xFFu;
            unsigned int p = (u == (unsigned int)i) ? v : u;
            if (rk == INF32) p = (unsigned int)i;  // safety; complete graph: unused
            par[s] = p;
            parentS[i] = (unsigned char)p;
        }
    }
    #pragma unroll
    for (int s = 0; s < 4; ++s) {         // break mutual 2-cycles
        const int i = lane + 64 * s;
        if (i < n) {
            const unsigned int p = par[s];
            if (p != (unsigned int)i) {
                if (parentS[p] == (unsigned char)i && (unsigned int)i < p) {
                    parentS[i] = (unsigned char)i;   // winner stays root, no death
                } else if (RECORD) {
                    const unsigned int d = atomicAdd(dcS, 1u);
                    const unsigned int rk = rowKeyS[i];
                    deaths[d] = sqrtf(__half2float(__ushort_as_half(
                        (unsigned short)(rk >> 16))));
                }
            }
        }
    }
    for (;;) {                            // async pointer jump (deterministic fixpoint)
        bool ch = false;
        #pragma unroll
        for (int s = 0; s < 4; ++s) {
            const int i = lane + 64 * s;
            if (i < n) {
                const unsigned char p0 = parentS[i];
                const unsigned char np = parentS[p0];
                if (np != p0) { ch = true; parentS[i] = np; }
            }
        }
        if (__ballot(ch) == 0ull) break;
    }
    // ballot-rank renumber: newid[root] = rank among roots (deterministic).
    // below = lanes strictly below me; (1ull<<lane)-1 is well-defined for lane<=63.
    // (R5 BUG: lane==63 used ~0ull which counts the lane itself -> id collision ->
    //  disconnected contracted graph -> infinite loop. Fixed.)
    bool isr[4];
    #pragma unroll
    for (int s = 0; s < 4; ++s) {
        const int i = lane + 64 * s;
        isr[s] = (i < n) && (parentS[i] == (unsigned char)i);
    }
    unsigned int base = 0;
    const unsigned long long below = (1ull << lane) - 1ull;
    #pragma unroll
    for (int s = 0; s < 4; ++s) {
        const unsigned long long mask = __ballot(isr[s]);   // uniform execution
        if (isr[s]) {
            const int i = lane + 64 * s;
            newidS[i] = (unsigned char)(base + __popcll(mask & below));
        }
        base += (unsigned int)__popcll(mask);
    }
    if (lane == 0) *ncS = base;
    #pragma unroll
    for (int s = 0; s < 4; ++s) {
        const int i = lane + 64 * s;
        if (i < n) cmapS[i] = newidS[parentS[i]];
    }
}

// ---------------- K3: distributed round-1 contraction ----------------
__global__ void __launch_bounds__(256) k_contract(const unsigned short* __restrict__ D16g,
                                                  const unsigned int* __restrict__ rowKeyG,
                                                  unsigned int* __restrict__ Mp) {
    __shared__ unsigned int rowKeyS[256];
    __shared__ unsigned char parentS[256], newidS[256], cmapS[256];
    __shared__ unsigned int ncS;
    const int tid = threadIdx.x;
    const int b = blockIdx.x;
    rowKeyS[tid] = rowKeyG[tid];
    __syncthreads();
    if (tid < 64)
        wave0_phase<false>(256, tid, rowKeyS, parentS, newidS, cmapS,
                           nullptr, &ncS, nullptr);
    __syncthreads();
    // fold row b into Mp via global atomicMin (distributed across 256 CUs)
    const unsigned int ca = cmapS[b];
    const unsigned int cb = cmapS[tid];
    if (ca != cb) {
        const unsigned int w16 = (unsigned int)D16g[b * 256 + tid];
        const unsigned int lo = ca < cb ? ca : cb;
        const unsigned int hi = ca < cb ? cb : ca;
        atomicMin(&Mp[ca * MPSTR + cb], (w16 << 16) | (lo << 8) | hi);
    }
}

// ---------------- K4: Boruvka rounds 2+ on contracted matrix + structure layer ----
#define SA 132   // u32 stride, buffer A (cap 128 rows)
#define SB 68    // u32 stride, buffer B (cap 64 rows)
#define OFF_B (128 * SA)

__global__ void __launch_bounds__(1024) k_mst(const unsigned int* __restrict__ Mp,
                                              const unsigned int* __restrict__ rowKeyG,
                                              const unsigned int* __restrict__ mm,
                                              const float* __restrict__ centres,
                                              const float* __restrict__ sharp,
                                              float* __restrict__ out) {
    __shared__ unsigned int Mb[128 * SA + 64 * SB];   // 85 KB ping-pong
    __shared__ unsigned int rowKeyS[256];
    __shared__ unsigned char parentS[256], newidS[256], cmapS[256];
    __shared__ unsigned int ncS, dcS;
    __shared__ float deaths[256];
    __shared__ float outpart[1024];
    const int tid = threadIdx.x;

    // round 1: re-hook from rowKeyG (deterministic; records deaths)
    if (tid < 256) rowKeyS[tid] = rowKeyG[tid];
    if (tid == 0) dcS = 0;
    __syncthreads();
    if (tid < 64)
        wave0_phase<true>(256, tid, rowKeyS, parentS, newidS, cmapS,
                          deaths, &ncS, &dcS);
    __syncthreads();
    int n = (int)ncS;

    // load contracted matrix Mp (n x n, stride MPSTR) into buffer A
    for (int idx = tid; idx < n * SA; idx += 1024) Mb[idx] = Mp[idx];
    __syncthreads();

    // rounds 2+ (bounded: Boruvka on <=256 nodes needs <=8 rounds; 12 = hang guard)
    int srcOff = 0, srcStr = SA, dstOff = OFF_B, dstStr = SB;
    for (int round = 0; round < 12 && n > 1; ++round) {
        if (tid < n) rowKeyS[tid] = INF32;
        __syncthreads();
        if (tid < 8 * n) {                 // scan: 8 threads per row
            const int a = tid >> 3, sub = tid & 7;
            const unsigned int* row = &Mb[srcOff + a * srcStr];
            unsigned int best = INF32;
            for (int b2 = sub; b2 < n; b2 += 8) {
                const unsigned int v = row[b2];
                best = v < best ? v : best;
            }
            if (best != INF32) atomicMin(&rowKeyS[a], best);
        }
        __syncthreads();
        if (tid < 64)
            wave0_phase<true>(n, tid, rowKeyS, parentS, newidS, cmapS,
                              deaths, &ncS, &dcS);
        __syncthreads();
        const int nc = (int)ncS;
        if (nc > 1) {                      // contract src -> dst
            for (int w = tid; w < nc * dstStr; w += 1024) Mb[dstOff + w] = INF32;
            __syncthreads();
            if (tid < 8 * n) {
                const int a = tid >> 3, sub = tid & 7;
                const unsigned int ca = cmapS[a];
                const unsigned int* row = &Mb[srcOff + a * srcStr];
                for (int b2 = sub; b2 < n; b2 += 8) {
                    const unsigned int cb = cmapS[b2];
                    const unsigned int v = row[b2];
                    if (ca != cb && v != INF32) {
                        const unsigned int lo = ca < cb ? ca : cb;
                        const unsigned int hi = ca < cb ? cb : ca;
                        atomicMin(&Mb[dstOff + ca * dstStr + cb],
                                  (v & 0xFFFF0000u) | (lo << 8) | hi);
                    }
                }
            }
            __syncthreads();
        }
        const int t1 = srcOff; srcOff = dstOff; dstOff = t1;
        const int t2 = srcStr; srcStr = dstStr; dstStr = t2;
        n = nc;
    }

    // structure-element layer
    const float mn = __uint_as_float(mm[0]);
    const float mx = __uint_as_float(mm[1]);
    const float inv = 1.0f / (mx - mn);
    const int k = tid & 63;
    const int part = tid >> 6;
    const float c0 = centres[2 * k], c1 = centres[2 * k + 1];
    const float s0 = sharp[2 * k],   s1 = sharp[2 * k + 1];
    const float t0 = c0 * c0 * s0 * s0;
    const float s1sq = s1 * s1;
    float acc = 0.f;
    for (int idx = part; idx < 255; idx += 16) {
        const float d = deaths[idx] * inv - c1;
        acc += __expf(-(t0 + d * d * s1sq));
    }
    outpart[tid] = acc;
    __syncthreads();
    if (tid < 64) {
        float s = 0.f;
        #pragma unroll
        for (int pp = 0; pp < 16; ++pp) s += outpart[tid + 64 * pp];
        out[tid] = s;
    }
}

extern "C" void kernel_launch(void* const* d_in, const int* in_sizes, int n_in,
                              void* d_out, int out_size, void* d_ws, size_t ws_size,
                              hipStream_t stream) {
    const float* x       = (const float*)d_in[0];
    const float* centres = (const float*)d_in[1];
    const float* sharp   = (const float*)d_in[2];
    float* out = (float*)d_out;
    char* ws = (char*)d_ws;
    float*          m   = (float*)(ws + WS_M);
    unsigned int*   mm  = (unsigned int*)(ws + WS_MM);
    unsigned int*   rk  = (unsigned int*)(ws + WS_RK);
    unsigned short* D16 = (unsigned short*)(ws + WS_D16);
    unsigned int*   Mp  = (unsigned int*)(ws + WS_MP);

    k_mean<<<256, 256, 0, stream>>>(x, m, Mp);
    k_dist<<<256, 256, 0, stream>>>(m, D16, rk, mm);
    k_contract<<<256, 256, 0, stream>>>(D16, rk, Mp);
    k_mst<<<1, 1024, 0, stream>>>(Mp, rk, mm, centres, sharp, out);
}